// Round 1
// baseline (1792.601 us; speedup 1.0000x reference)
//
#include <hip/hip_runtime.h>
#include <math.h>

#define NG 7
#define SGR 12
#define NP 49          // patches per image
#define NA 18          // action space
#define NB 8192        // batch
#define F1 144         // patch features
#define F2 288         // e-MLP input features
#define TOTAL (NB*NP)  // 401408 MLP rows
#define ROWS 32        // rows per block (TOTAL % ROWS == 0)
#define NBLK (TOTAL/ROWS)

// ---------------------------------------------------------------------------
// Kernel A: per-(batch,patch) row: stage patch to LDS, run alpha-MLP and
// e-MLP, write alpha logits to ws and per-patch log_softmax to out_each.
// 256 threads / 32 rows. Activation reads are wave-uniform LDS broadcasts.
// LDS aliasing: Xs[32][288] | H1[32][256]; HA1/HA2 live inside H1 region,
// H2/Eo/Rm/Rl live inside Xs region (dead after e1). Total 69,632 B -> 2 blk/CU.
// ---------------------------------------------------------------------------
__global__ __launch_bounds__(256, 2)
void fused_mlp_kernel(const float* __restrict__ last_s, const float* __restrict__ now_s,
                      const float* __restrict__ We1, const float* __restrict__ be1,
                      const float* __restrict__ We2, const float* __restrict__ be2,
                      const float* __restrict__ We3, const float* __restrict__ be3,
                      const float* __restrict__ Wa1, const float* __restrict__ ba1,
                      const float* __restrict__ Wa2, const float* __restrict__ ba2,
                      const float* __restrict__ Wa3, const float* __restrict__ ba3,
                      float* __restrict__ out_each, float* __restrict__ ws_alpha)
{
    __shared__ float smem[17408];
    float* Xs  = smem;           // [32][288] patch features (diff | now)
    float* H1  = smem + 9216;    // [32][256] e-layer1 out
    float* HA1 = H1;             // [32][64]  alpha-layer1 out (aliases H1)
    float* HA2 = H1 + 2048;      // [32][64]  alpha-layer2 out
    float* H2  = smem;           // [32][128] e-layer2 out (aliases Xs)
    float* Eo  = smem + 4096;    // [32][18]  e logits
    float* Rm  = smem + 4672;    // [32] row max
    float* Rl  = smem + 4704;    // [32] row log-sum-exp

    const int t    = threadIdx.x;
    const int row0 = blockIdx.x * ROWS;
    const int cg   = t & 63;        // col group within wave
    const int rg8  = (t >> 6) * 8;  // first row of this thread's 8-row slice

    // ---- stage patches: Xs[r][0:144]=diff, Xs[r][144:288]=now ----
    for (int idx = t; idx < ROWS * F1; idx += 256) {
        const int r  = idx / F1, f = idx - r * F1;
        const int row = row0 + r;
        const int b  = row / NP, p = row - b * NP;
        const int i  = p / NG,  j = p - i * NG;
        const int fr = f / SGR, fc = f - fr * SGR;
        const int addr = (b * 84 + i * SGR + fr) * 84 + j * SGR + fc;
        const float nv = now_s[addr]  * (1.0f / 255.0f);
        const float lv = last_s[addr] * (1.0f / 255.0f);
        Xs[r * F2 + f]      = nv - lv;
        Xs[r * F2 + F1 + f] = nv;
    }
    __syncthreads();

    // ---- alpha layer 1: 144 -> 64, relu (input = "now" half of Xs) ----
    {
        float acc[8];
        const float bias = ba1[cg];
        #pragma unroll
        for (int ri = 0; ri < 8; ++ri) acc[ri] = bias;
        for (int k = 0; k < 144; k += 4) {
            float4 xv[8];
            #pragma unroll
            for (int ri = 0; ri < 8; ++ri)
                xv[ri] = *(const float4*)(Xs + (rg8 + ri) * F2 + F1 + k);
            #pragma unroll
            for (int kk = 0; kk < 4; ++kk) {
                const float w = Wa1[(k + kk) * 64 + cg];
                #pragma unroll
                for (int ri = 0; ri < 8; ++ri)
                    acc[ri] = fmaf(((const float*)(xv + ri))[kk], w, acc[ri]);
            }
        }
        #pragma unroll
        for (int ri = 0; ri < 8; ++ri)
            HA1[(rg8 + ri) * 64 + cg] = fmaxf(acc[ri], 0.0f);
    }
    __syncthreads();

    // ---- alpha layer 2: 64 -> 64, relu ----
    {
        float acc[8];
        const float bias = ba2[cg];
        #pragma unroll
        for (int ri = 0; ri < 8; ++ri) acc[ri] = bias;
        for (int k = 0; k < 64; k += 4) {
            float4 xv[8];
            #pragma unroll
            for (int ri = 0; ri < 8; ++ri)
                xv[ri] = *(const float4*)(HA1 + (rg8 + ri) * 64 + k);
            #pragma unroll
            for (int kk = 0; kk < 4; ++kk) {
                const float w = Wa2[(k + kk) * 64 + cg];
                #pragma unroll
                for (int ri = 0; ri < 8; ++ri)
                    acc[ri] = fmaf(((const float*)(xv + ri))[kk], w, acc[ri]);
            }
        }
        #pragma unroll
        for (int ri = 0; ri < 8; ++ri)
            HA2[(rg8 + ri) * 64 + cg] = fmaxf(acc[ri], 0.0f);
    }
    __syncthreads();

    // ---- alpha layer 3: 64 -> 1 ----
    if (t < ROWS) {
        float acc = ba3[0];
        for (int k = 0; k < 64; k += 4) {
            const float4 xv = *(const float4*)(HA2 + t * 64 + k);
            const float4 wv = *(const float4*)(Wa3 + k);
            acc = fmaf(xv.x, wv.x, fmaf(xv.y, wv.y, fmaf(xv.z, wv.z, fmaf(xv.w, wv.w, acc))));
        }
        ws_alpha[row0 + t] = acc;
    }
    __syncthreads();   // HA2 dead; H1 region reusable

    // ---- e layer 1: 288 -> 256, relu (4 cols x 8 rows per thread) ----
    {
        const int c0 = cg * 4;
        float4 acc[8];
        const float4 bv = *(const float4*)(be1 + c0);
        #pragma unroll
        for (int ri = 0; ri < 8; ++ri) acc[ri] = bv;
        for (int k = 0; k < 288; k += 4) {
            float4 xv[8];
            #pragma unroll
            for (int ri = 0; ri < 8; ++ri)
                xv[ri] = *(const float4*)(Xs + (rg8 + ri) * F2 + k);
            #pragma unroll
            for (int kk = 0; kk < 4; ++kk) {
                const float4 wv = *(const float4*)(We1 + (k + kk) * 256 + c0);
                #pragma unroll
                for (int ri = 0; ri < 8; ++ri) {
                    const float x = ((const float*)(xv + ri))[kk];
                    acc[ri].x = fmaf(x, wv.x, acc[ri].x);
                    acc[ri].y = fmaf(x, wv.y, acc[ri].y);
                    acc[ri].z = fmaf(x, wv.z, acc[ri].z);
                    acc[ri].w = fmaf(x, wv.w, acc[ri].w);
                }
            }
        }
        #pragma unroll
        for (int ri = 0; ri < 8; ++ri) {
            float4 r4;
            r4.x = fmaxf(acc[ri].x, 0.0f); r4.y = fmaxf(acc[ri].y, 0.0f);
            r4.z = fmaxf(acc[ri].z, 0.0f); r4.w = fmaxf(acc[ri].w, 0.0f);
            *(float4*)(H1 + (rg8 + ri) * 256 + c0) = r4;
        }
    }
    __syncthreads();   // Xs dead; H2 may overlay it

    // ---- e layer 2: 256 -> 128, relu (2 cols x 8 rows per thread) ----
    {
        const int c0 = cg * 2;
        float2 acc[8];
        const float2 bv = *(const float2*)(be2 + c0);
        #pragma unroll
        for (int ri = 0; ri < 8; ++ri) acc[ri] = bv;
        for (int k = 0; k < 256; k += 4) {
            float4 xv[8];
            #pragma unroll
            for (int ri = 0; ri < 8; ++ri)
                xv[ri] = *(const float4*)(H1 + (rg8 + ri) * 256 + k);
            #pragma unroll
            for (int kk = 0; kk < 4; ++kk) {
                const float2 wv = *(const float2*)(We2 + (k + kk) * 128 + c0);
                #pragma unroll
                for (int ri = 0; ri < 8; ++ri) {
                    const float x = ((const float*)(xv + ri))[kk];
                    acc[ri].x = fmaf(x, wv.x, acc[ri].x);
                    acc[ri].y = fmaf(x, wv.y, acc[ri].y);
                }
            }
        }
        #pragma unroll
        for (int ri = 0; ri < 8; ++ri) {
            float2 r2;
            r2.x = fmaxf(acc[ri].x, 0.0f); r2.y = fmaxf(acc[ri].y, 0.0f);
            *(float2*)(H2 + (rg8 + ri) * 128 + c0) = r2;
        }
    }
    __syncthreads();

    // ---- e layer 3: 128 -> 18 (576 outputs, strided over threads) ----
    for (int o = t; o < ROWS * NA; o += 256) {
        const int r = o / NA, c = o - r * NA;
        float acc = be3[c];
        for (int k = 0; k < 128; k += 4) {
            const float4 xv = *(const float4*)(H2 + r * 128 + k);
            acc = fmaf(xv.x, We3[(k    ) * NA + c],
                  fmaf(xv.y, We3[(k + 1) * NA + c],
                  fmaf(xv.z, We3[(k + 2) * NA + c],
                  fmaf(xv.w, We3[(k + 3) * NA + c], acc))));
        }
        Eo[o] = acc;
    }
    __syncthreads();

    // ---- per-row max / log-sum-exp ----
    if (t < ROWS) {
        float m = -3.0e38f;
        #pragma unroll
        for (int a = 0; a < NA; ++a) m = fmaxf(m, Eo[t * NA + a]);
        float s = 0.0f;
        #pragma unroll
        for (int a = 0; a < NA; ++a) s += expf(Eo[t * NA + a] - m);
        Rm[t] = m; Rl[t] = logf(s);
    }
    __syncthreads();

    // ---- write per-patch log-softmax ----
    for (int o = t; o < ROWS * NA; o += 256) {
        const int r = o / NA;
        out_each[(size_t)(row0) * NA + o] = Eo[o] - Rm[r] - Rl[r];
    }
}

// ---------------------------------------------------------------------------
// Kernel B: one wave per batch element. Alpha softmax + entropy, alpha-weighted
// sum of out_each (valid since sum_p alpha_p*lse_p is constant over actions),
// final log_softmax -> out_probs.
// ---------------------------------------------------------------------------
__global__ __launch_bounds__(64)
void alpha_combine_kernel(const float* __restrict__ ws_alpha,
                          const float* __restrict__ out_each,
                          float* __restrict__ out_probs,
                          float* __restrict__ ws_ent)
{
    const int b = blockIdx.x;
    const int lane = threadIdx.x;

    float lg = (lane < NP) ? ws_alpha[b * NP + lane] : -3.0e38f;
    float m = lg;
    #pragma unroll
    for (int off = 32; off > 0; off >>= 1) m = fmaxf(m, __shfl_xor(m, off, 64));
    float ex = (lane < NP) ? expf(lg - m) : 0.0f;
    float s = ex;
    #pragma unroll
    for (int off = 32; off > 0; off >>= 1) s += __shfl_xor(s, off, 64);
    const float ls = logf(s);
    const float alpha = ex / s;

    float ent = (lane < NP) ? alpha * (lg - m - ls) : 0.0f;
    #pragma unroll
    for (int off = 32; off > 0; off >>= 1) ent += __shfl_xor(ent, off, 64);
    if (lane == 0) ws_ent[b] = ent;

    // alpha-weighted sum of per-patch log-softmax (== of e, up to an
    // action-independent shift that log_softmax cancels)
    float acc = 0.0f;
    const float* eb = out_each + (size_t)b * NP * NA;
    for (int p = 0; p < NP; ++p) {
        const float ap = __shfl(alpha, p, 64);
        if (lane < NA) acc += ap * eb[p * NA + lane];
    }
    float mm = (lane < NA) ? acc : -3.0e38f;
    #pragma unroll
    for (int off = 32; off > 0; off >>= 1) mm = fmaxf(mm, __shfl_xor(mm, off, 64));
    float ee = (lane < NA) ? expf(acc - mm) : 0.0f;
    #pragma unroll
    for (int off = 32; off > 0; off >>= 1) ee += __shfl_xor(ee, off, 64);
    if (lane < NA) out_probs[b * NA + lane] = acc - mm - logf(ee);
}

// ---------------------------------------------------------------------------
// Kernel C: mean of per-batch entropy partials -> scalar loss_ent.
// ---------------------------------------------------------------------------
__global__ __launch_bounds__(256)
void ent_reduce_kernel(const float* __restrict__ ws_ent, float* __restrict__ out_scalar)
{
    float s = 0.0f;
    for (int i = threadIdx.x; i < NB; i += 256) s += ws_ent[i];
    #pragma unroll
    for (int off = 32; off > 0; off >>= 1) s += __shfl_xor(s, off, 64);
    __shared__ float ps[4];
    if ((threadIdx.x & 63) == 0) ps[threadIdx.x >> 6] = s;
    __syncthreads();
    if (threadIdx.x == 0)
        out_scalar[0] = (ps[0] + ps[1] + ps[2] + ps[3]) * (1.0f / NB);
}

extern "C" void kernel_launch(void* const* d_in, const int* in_sizes, int n_in,
                              void* d_out, int out_size, void* d_ws, size_t ws_size,
                              hipStream_t stream)
{
    (void)in_sizes; (void)n_in; (void)out_size; (void)ws_size;

    const float* last_s = (const float*)d_in[0];
    const float* now_s  = (const float*)d_in[1];
    const float* We1 = (const float*)d_in[2];  const float* be1 = (const float*)d_in[3];
    const float* We2 = (const float*)d_in[4];  const float* be2 = (const float*)d_in[5];
    const float* We3 = (const float*)d_in[6];  const float* be3 = (const float*)d_in[7];
    const float* Wa1 = (const float*)d_in[8];  const float* ba1 = (const float*)d_in[9];
    const float* Wa2 = (const float*)d_in[10]; const float* ba2 = (const float*)d_in[11];
    const float* Wa3 = (const float*)d_in[12]; const float* ba3 = (const float*)d_in[13];

    float* out = (float*)d_out;
    float* out_probs = out;                    // [B,18]
    float* out_ent   = out + NB * NA;          // scalar at 147456
    float* out_each  = out + NB * NA + 1;      // [B,49,18] at 147457

    float* ws_alpha = (float*)d_ws;            // [B*49] alpha logits
    float* ws_ent   = ws_alpha + TOTAL;        // [B] entropy partials

    fused_mlp_kernel<<<dim3(NBLK), dim3(256), 0, stream>>>(
        last_s, now_s, We1, be1, We2, be2, We3, be3,
        Wa1, ba1, Wa2, ba2, Wa3, ba3, out_each, ws_alpha);

    alpha_combine_kernel<<<dim3(NB), dim3(64), 0, stream>>>(
        ws_alpha, out_each, out_probs, ws_ent);

    ent_reduce_kernel<<<dim3(1), dim3(256), 0, stream>>>(ws_ent, out_ent);
}

// Round 2
// 461.344 us; speedup vs baseline: 3.8856x; 3.8856x over previous
//
#include <hip/hip_runtime.h>
#include <math.h>

#define NPCH 49
#define NA 18
#define NB 8192
#define TOTAL (NB*NPCH)    // 401408
#define RB 64              // rows per block
#define NBLK (TOTAL/RB)    // 6272

typedef __attribute__((ext_vector_type(8))) short bf16x8;
typedef __attribute__((ext_vector_type(4))) float f32x4;

__device__ __forceinline__ unsigned short f2bf(float f) {
    unsigned int u = __float_as_uint(f);
    return (unsigned short)((u + 0x7FFFu + ((u >> 16) & 1u)) >> 16);
}

// bf16 weight buffer layout (ushort units), built by prep_weights
#define W1_OFF  0          // We1t [256][288]
#define W2_OFF  73728      // We2t [128][256]
#define W3_OFF  106496     // We3t [32][128]  (rows 18..31 zero)
#define WA1_OFF 110592     // Wa1t [64][160]  (k 144..159 zero)
#define WA2_OFF 120832     // Wa2t [64][64]
#define W_TOTAL 124928

__global__ __launch_bounds__(256)
void prep_weights(const float* __restrict__ We1, const float* __restrict__ We2,
                  const float* __restrict__ We3, const float* __restrict__ Wa1,
                  const float* __restrict__ Wa2, unsigned short* __restrict__ wb)
{
    int i = blockIdx.x * 256 + threadIdx.x;
    if (i >= W_TOTAL) return;
    int idx = i;
    float v;
    if (idx < 73728) {                       // We1t[n][k] = We1[k][n], 288x256
        int n = idx / 288, k = idx - n * 288;
        v = We1[k * 256 + n];
    } else if ((idx -= 73728) < 32768) {     // We2t, 256x128
        int n = idx / 256, k = idx - n * 256;
        v = We2[k * 128 + n];
    } else if ((idx -= 32768) < 4096) {      // We3t, 128x18 padded to 32 cols
        int n = idx / 128, k = idx - n * 128;
        v = (n < 18) ? We3[k * 18 + n] : 0.0f;
    } else if ((idx -= 4096) < 10240) {      // Wa1t, 144x64 padded to K=160
        int n = idx / 160, k = idx - n * 160;
        v = (k < 144) ? Wa1[k * 64 + n] : 0.0f;
    } else {                                 // Wa2t, 64x64
        idx -= 10240;
        int n = idx / 64, k = idx - n * 64;
        v = Wa2[k * 64 + n];
    }
    wb[i] = f2bf(v);
}

// ---------------------------------------------------------------------------
// Fused MFMA kernel: 64 rows/block, 4 waves splitting N.
// LDS (50176 B): Ein frags [4rt][10s][512]us @0 (40960); H1 [4][8][512] overlays
// @0 (32768); H2 [4][4][512] @32768 (16384, overlays HA1 tail); HA1 [4][2][512]
// @40960 (8192); alpha partials [4][64]f32 @49152 (1024). 3 blocks/CU.
// A-frag = lane-linear (read/write at lane*16B: conflict-free).
// ---------------------------------------------------------------------------
__global__ __launch_bounds__(256)
void fused_mfma_kernel(const float* __restrict__ last_s, const float* __restrict__ now_s,
                       const unsigned short* __restrict__ wb,
                       const float* __restrict__ be1, const float* __restrict__ be2,
                       const float* __restrict__ be3, const float* __restrict__ ba1,
                       const float* __restrict__ ba2, const float* __restrict__ ba3,
                       const float* __restrict__ Wa3,
                       float* __restrict__ out_each, float* __restrict__ ws_alpha)
{
    __shared__ __align__(16) unsigned char smem[50176];
    unsigned short* Ein = (unsigned short*)smem;            // [4][10][512]
    unsigned short* H1  = (unsigned short*)smem;            // [4][8][512] overlay
    unsigned short* H2  = (unsigned short*)(smem + 32768);  // [4][4][512]
    unsigned short* HA1 = (unsigned short*)(smem + 40960);  // [4][2][512]
    float*          APT = (float*)(smem + 49152);           // [4][64]

    const int t    = threadIdx.x;
    const int lane = t & 63;
    const int wid  = t >> 6;
    const int g    = lane >> 4;
    const int rl   = lane & 15;
    const int row0 = blockIdx.x * RB;

    // ---------------- stage patches into A-fragment layout ----------------
    {
        const int R  = row0 + wid * 16 + rl;
        const int b  = R / NPCH, p = R - b * NPCH;
        const int pi = p / 7,    pj = p - pi * 7;
        const float* nowp  = now_s  + (size_t)b * 7056 + pi * 1008 + pj * 12;
        const float* lastp = last_s + (size_t)b * 7056 + pi * 1008 + pj * 12;
        bf16x8 z = {0, 0, 0, 0, 0, 0, 0, 0};
        *(bf16x8*)(Ein + (wid * 10 + 9) * 512 + lane * 8) = z;   // zero pad slot
        for (int s = 0; s < 9; ++s) {
            union { unsigned short u[8]; bf16x8 v; } pk;
            #pragma unroll
            for (int j = 0; j < 8; ++j) {
                int k = s * 32 + g * 8 + j;
                float v;
                if (k < 144) {
                    int fr = k / 12, fc = k - fr * 12;
                    int off = fr * 84 + fc;
                    v = (nowp[off] - lastp[off]) * (1.0f / 255.0f);
                } else {
                    int f = k - 144;
                    int fr = f / 12, fc = f - fr * 12;
                    v = nowp[fr * 84 + fc] * (1.0f / 255.0f);
                }
                pk.u[j] = f2bf(v);
            }
            *(bf16x8*)(Ein + (wid * 10 + s) * 512 + lane * 8) = pk.v;
        }
    }
    __syncthreads();

    // ---------------- alpha layer 1: 144(->160) -> 64 ----------------
    {
        const int col = wid * 16 + rl;
        const float b1 = ba1[col];
        f32x4 acc[4];
        #pragma unroll
        for (int mt = 0; mt < 4; ++mt) acc[mt] = (f32x4){b1, b1, b1, b1};
        for (int sa = 0; sa < 5; ++sa) {
            const int ok = 144 + sa * 32 + g * 8;   // offset into Ein's "now" half
            bf16x8 bfr = *(const bf16x8*)(wb + WA1_OFF + col * 160 + sa * 32 + g * 8);
            #pragma unroll
            for (int mt = 0; mt < 4; ++mt) {
                bf16x8 af = *(const bf16x8*)(Ein + (mt * 10 + (ok >> 5)) * 512 +
                                             ((ok >> 3) & 3) * 128 + rl * 8);
                acc[mt] = __builtin_amdgcn_mfma_f32_16x16x32_bf16(af, bfr, acc[mt], 0, 0, 0);
            }
        }
        const int sA  = wid >> 1;
        const int hiA = (wid & 1) * 2 + (rl >> 3);
        const int jA  = rl & 7;
        #pragma unroll
        for (int mt = 0; mt < 4; ++mt) {
            unsigned short* base = HA1 + (mt * 2 + sA) * 512 + hiA * 128 + (g * 4) * 8 + jA;
            #pragma unroll
            for (int r = 0; r < 4; ++r)
                base[r * 8] = f2bf(fmaxf(acc[mt][r], 0.0f));
        }
    }
    __syncthreads();

    // ---------------- alpha layer 2 + fused layer 3 ----------------
    {
        const int col = wid * 16 + rl;
        const float b2 = ba2[col];
        const float w3 = Wa3[col];
        f32x4 acc[4];
        #pragma unroll
        for (int mt = 0; mt < 4; ++mt) acc[mt] = (f32x4){b2, b2, b2, b2};
        for (int s = 0; s < 2; ++s) {
            bf16x8 bfr = *(const bf16x8*)(wb + WA2_OFF + col * 64 + s * 32 + g * 8);
            #pragma unroll
            for (int mt = 0; mt < 4; ++mt) {
                bf16x8 af = *(const bf16x8*)(HA1 + (mt * 2 + s) * 512 + lane * 8);
                acc[mt] = __builtin_amdgcn_mfma_f32_16x16x32_bf16(af, bfr, acc[mt], 0, 0, 0);
            }
        }
        #pragma unroll
        for (int mt = 0; mt < 4; ++mt) {
            #pragma unroll
            for (int r = 0; r < 4; ++r) {
                float v = fmaxf(acc[mt][r], 0.0f) * w3;
                v += __shfl_xor(v, 1); v += __shfl_xor(v, 2);
                v += __shfl_xor(v, 4); v += __shfl_xor(v, 8);
                if (rl == 0) APT[wid * 64 + mt * 16 + g * 4 + r] = v;
            }
        }
    }
    __syncthreads();

    // alpha logits finalize
    if (t < RB)
        ws_alpha[row0 + t] = APT[t] + APT[64 + t] + APT[128 + t] + APT[192 + t] + ba3[0];

    // ---------------- e layer 1: 288 -> 256 ----------------
    f32x4 acc1[4][4];
    {
        #pragma unroll
        for (int nt = 0; nt < 4; ++nt) {
            const float b = be1[wid * 64 + nt * 16 + rl];
            #pragma unroll
            for (int mt = 0; mt < 4; ++mt) acc1[mt][nt] = (f32x4){b, b, b, b};
        }
        for (int s = 0; s < 9; ++s) {
            bf16x8 a0f = *(const bf16x8*)(Ein + (0 * 10 + s) * 512 + lane * 8);
            bf16x8 a1f = *(const bf16x8*)(Ein + (1 * 10 + s) * 512 + lane * 8);
            bf16x8 a2f = *(const bf16x8*)(Ein + (2 * 10 + s) * 512 + lane * 8);
            bf16x8 a3f = *(const bf16x8*)(Ein + (3 * 10 + s) * 512 + lane * 8);
            #pragma unroll
            for (int nt = 0; nt < 4; ++nt) {
                bf16x8 bfr = *(const bf16x8*)(wb + W1_OFF +
                                (wid * 64 + nt * 16 + rl) * 288 + s * 32 + g * 8);
                acc1[0][nt] = __builtin_amdgcn_mfma_f32_16x16x32_bf16(a0f, bfr, acc1[0][nt], 0, 0, 0);
                acc1[1][nt] = __builtin_amdgcn_mfma_f32_16x16x32_bf16(a1f, bfr, acc1[1][nt], 0, 0, 0);
                acc1[2][nt] = __builtin_amdgcn_mfma_f32_16x16x32_bf16(a2f, bfr, acc1[2][nt], 0, 0, 0);
                acc1[3][nt] = __builtin_amdgcn_mfma_f32_16x16x32_bf16(a3f, bfr, acc1[3][nt], 0, 0, 0);
            }
        }
    }
    __syncthreads();    // all Ein reads complete before H1 overlay

    // H1 fragment writes (relu)
    {
        #pragma unroll
        for (int mt = 0; mt < 4; ++mt) {
            #pragma unroll
            for (int nt = 0; nt < 4; ++nt) {
                const int col = wid * 64 + nt * 16 + rl;
                unsigned short* base = H1 + (mt * 8 + (col >> 5)) * 512 +
                                       ((col >> 3) & 3) * 128 + (g * 4) * 8 + (col & 7);
                #pragma unroll
                for (int r = 0; r < 4; ++r)
                    base[r * 8] = f2bf(fmaxf(acc1[mt][nt][r], 0.0f));
            }
        }
    }
    __syncthreads();

    // ---------------- e layer 2: 256 -> 128 ----------------
    {
        f32x4 acc2[4][2];
        #pragma unroll
        for (int nt = 0; nt < 2; ++nt) {
            const float b = be2[wid * 32 + nt * 16 + rl];
            #pragma unroll
            for (int mt = 0; mt < 4; ++mt) acc2[mt][nt] = (f32x4){b, b, b, b};
        }
        for (int s = 0; s < 8; ++s) {
            bf16x8 a0f = *(const bf16x8*)(H1 + (0 * 8 + s) * 512 + lane * 8);
            bf16x8 a1f = *(const bf16x8*)(H1 + (1 * 8 + s) * 512 + lane * 8);
            bf16x8 a2f = *(const bf16x8*)(H1 + (2 * 8 + s) * 512 + lane * 8);
            bf16x8 a3f = *(const bf16x8*)(H1 + (3 * 8 + s) * 512 + lane * 8);
            #pragma unroll
            for (int nt = 0; nt < 2; ++nt) {
                bf16x8 bfr = *(const bf16x8*)(wb + W2_OFF +
                                (wid * 32 + nt * 16 + rl) * 256 + s * 32 + g * 8);
                acc2[0][nt] = __builtin_amdgcn_mfma_f32_16x16x32_bf16(a0f, bfr, acc2[0][nt], 0, 0, 0);
                acc2[1][nt] = __builtin_amdgcn_mfma_f32_16x16x32_bf16(a1f, bfr, acc2[1][nt], 0, 0, 0);
                acc2[2][nt] = __builtin_amdgcn_mfma_f32_16x16x32_bf16(a2f, bfr, acc2[2][nt], 0, 0, 0);
                acc2[3][nt] = __builtin_amdgcn_mfma_f32_16x16x32_bf16(a3f, bfr, acc2[3][nt], 0, 0, 0);
            }
        }
        // H2 fragment writes (relu); region disjoint from H1 -> no barrier first
        #pragma unroll
        for (int mt = 0; mt < 4; ++mt) {
            #pragma unroll
            for (int nt = 0; nt < 2; ++nt) {
                const int c2 = nt * 16 + rl;   // col = wid*32 + c2, s2 = wid
                unsigned short* base = H2 + (mt * 4 + wid) * 512 +
                                       ((c2 >> 3) & 3) * 128 + (g * 4) * 8 + (c2 & 7);
                #pragma unroll
                for (int r = 0; r < 4; ++r)
                    base[r * 8] = f2bf(fmaxf(acc2[mt][nt][r], 0.0f));
            }
        }
    }
    __syncthreads();

    // ---------------- e layer 3: 128 -> 18 (padded 32) + log_softmax ----------------
    {
        f32x4 acc3[2];
        #pragma unroll
        for (int nt = 0; nt < 2; ++nt) {
            const int col = nt * 16 + rl;
            const float b = (col < NA) ? be3[col] : 0.0f;
            acc3[nt] = (f32x4){b, b, b, b};
        }
        for (int s = 0; s < 4; ++s) {
            bf16x8 af = *(const bf16x8*)(H2 + (wid * 4 + s) * 512 + lane * 8);
            #pragma unroll
            for (int nt = 0; nt < 2; ++nt) {
                bf16x8 bfr = *(const bf16x8*)(wb + W3_OFF + (nt * 16 + rl) * 128 + s * 32 + g * 8);
                acc3[nt] = __builtin_amdgcn_mfma_f32_16x16x32_bf16(af, bfr, acc3[nt], 0, 0, 0);
            }
        }
        const bool v1 = (rl < 2);
        #pragma unroll
        for (int r = 0; r < 4; ++r) {
            float x0 = acc3[0][r];
            float x1 = acc3[1][r];
            float m = fmaxf(x0, v1 ? x1 : -3.0e38f);
            m = fmaxf(m, __shfl_xor(m, 1)); m = fmaxf(m, __shfl_xor(m, 2));
            m = fmaxf(m, __shfl_xor(m, 4)); m = fmaxf(m, __shfl_xor(m, 8));
            float sm = expf(x0 - m) + (v1 ? expf(x1 - m) : 0.0f);
            sm += __shfl_xor(sm, 1); sm += __shfl_xor(sm, 2);
            sm += __shfl_xor(sm, 4); sm += __shfl_xor(sm, 8);
            const float L = m + logf(sm);
            float* o = out_each + (size_t)(row0 + wid * 16 + g * 4 + r) * NA;
            o[rl] = x0 - L;
            if (v1) o[16 + rl] = x1 - L;
        }
    }
}

// ---------------------------------------------------------------------------
// Kernel B: one wave per batch element (unchanged from validated R1 version).
// ---------------------------------------------------------------------------
__global__ __launch_bounds__(64)
void alpha_combine_kernel(const float* __restrict__ ws_alpha,
                          const float* __restrict__ out_each,
                          float* __restrict__ out_probs,
                          float* __restrict__ ws_ent)
{
    const int b = blockIdx.x;
    const int lane = threadIdx.x;

    float lg = (lane < NPCH) ? ws_alpha[b * NPCH + lane] : -3.0e38f;
    float m = lg;
    #pragma unroll
    for (int off = 32; off > 0; off >>= 1) m = fmaxf(m, __shfl_xor(m, off, 64));
    float ex = (lane < NPCH) ? expf(lg - m) : 0.0f;
    float s = ex;
    #pragma unroll
    for (int off = 32; off > 0; off >>= 1) s += __shfl_xor(s, off, 64);
    const float ls = logf(s);
    const float alpha = ex / s;

    float ent = (lane < NPCH) ? alpha * (lg - m - ls) : 0.0f;
    #pragma unroll
    for (int off = 32; off > 0; off >>= 1) ent += __shfl_xor(ent, off, 64);
    if (lane == 0) ws_ent[b] = ent;

    float acc = 0.0f;
    const float* eb = out_each + (size_t)b * NPCH * NA;
    for (int p = 0; p < NPCH; ++p) {
        const float ap = __shfl(alpha, p, 64);
        if (lane < NA) acc += ap * eb[p * NA + lane];
    }
    float mm = (lane < NA) ? acc : -3.0e38f;
    #pragma unroll
    for (int off = 32; off > 0; off >>= 1) mm = fmaxf(mm, __shfl_xor(mm, off, 64));
    float ee = (lane < NA) ? expf(acc - mm) : 0.0f;
    #pragma unroll
    for (int off = 32; off > 0; off >>= 1) ee += __shfl_xor(ee, off, 64);
    if (lane < NA) out_probs[b * NA + lane] = acc - mm - logf(ee);
}

__global__ __launch_bounds__(256)
void ent_reduce_kernel(const float* __restrict__ ws_ent, float* __restrict__ out_scalar)
{
    float s = 0.0f;
    for (int i = threadIdx.x; i < NB; i += 256) s += ws_ent[i];
    #pragma unroll
    for (int off = 32; off > 0; off >>= 1) s += __shfl_xor(s, off, 64);
    __shared__ float ps[4];
    if ((threadIdx.x & 63) == 0) ps[threadIdx.x >> 6] = s;
    __syncthreads();
    if (threadIdx.x == 0)
        out_scalar[0] = (ps[0] + ps[1] + ps[2] + ps[3]) * (1.0f / NB);
}

extern "C" void kernel_launch(void* const* d_in, const int* in_sizes, int n_in,
                              void* d_out, int out_size, void* d_ws, size_t ws_size,
                              hipStream_t stream)
{
    (void)in_sizes; (void)n_in; (void)out_size; (void)ws_size;

    const float* last_s = (const float*)d_in[0];
    const float* now_s  = (const float*)d_in[1];
    const float* We1 = (const float*)d_in[2];  const float* be1 = (const float*)d_in[3];
    const float* We2 = (const float*)d_in[4];  const float* be2 = (const float*)d_in[5];
    const float* We3 = (const float*)d_in[6];  const float* be3 = (const float*)d_in[7];
    const float* Wa1 = (const float*)d_in[8];  const float* ba1 = (const float*)d_in[9];
    const float* Wa2 = (const float*)d_in[10]; const float* ba2 = (const float*)d_in[11];
    const float* Wa3 = (const float*)d_in[12]; const float* ba3 = (const float*)d_in[13];

    float* out = (float*)d_out;
    float* out_probs = out;                    // [B,18]
    float* out_ent   = out + NB * NA;          // scalar
    float* out_each  = out + NB * NA + 1;      // [B,49,18]

    float* ws_alpha = (float*)d_ws;            // [TOTAL]
    float* ws_ent   = ws_alpha + TOTAL;        // [NB]
    unsigned short* wbuf = (unsigned short*)(ws_ent + NB);  // bf16 weights

    prep_weights<<<dim3((W_TOTAL + 255) / 256), dim3(256), 0, stream>>>(
        We1, We2, We3, Wa1, Wa2, wbuf);

    fused_mfma_kernel<<<dim3(NBLK), dim3(256), 0, stream>>>(
        last_s, now_s, wbuf, be1, be2, be3, ba1, ba2, ba3, Wa3,
        out_each, ws_alpha);

    alpha_combine_kernel<<<dim3(NB), dim3(64), 0, stream>>>(
        ws_alpha, out_each, out_probs, ws_ent);

    ent_reduce_kernel<<<dim3(1), dim3(256), 0, stream>>>(ws_ent, out_ent);
}